// Round 11
// baseline (344.293 us; speedup 1.0000x reference)
//
#include <hip/hip_runtime.h>

typedef _Float16 f16;
typedef _Float16 f16x2 __attribute__((ext_vector_type(2)));
typedef _Float16 f16x8 __attribute__((ext_vector_type(8)));
typedef float f32x4 __attribute__((ext_vector_type(4)));
typedef unsigned int u32;
typedef unsigned int u32x4 __attribute__((ext_vector_type(4)));

static __device__ __forceinline__ u32 pk2(float lo, float hi) {
  union { f16 h[2]; u32 u; } v;
  v.h[0] = (f16)lo; v.h[1] = (f16)hi;
  return v.u;
}

// ---- fused prep: blocks 0..2047: W[f,d,e]->fp16 retile;
//      blocks 2048..2111: decayed prefix scan of x -> st (transposed).
// W layout: byte = d*32768 + (e>>5)*8192 + f*64 + ((e>>3)&3)*16 + (e&7)*2
__global__ void k_pre(const float* __restrict__ W, char* __restrict__ wt,
                      const float* __restrict__ x, float* __restrict__ st) {
  int bid = blockIdx.x;
  if (bid < 2048) {
    int t = bid * 256 + threadIdx.x;
    long i = (long)t * 4;                      // 2M W elements, 4/thread
    int f = (int)(i >> 14);
    int k = (int)(i & 16383);
    float4 w4 = *(const float4*)(W + i);
    int d = k >> 7, e = k & 127;
    long byo = (long)d * 32768 + (e >> 5) * 8192 + f * 64 + ((e >> 3) & 3) * 16 + (e & 7) * 2;
    u32* dst = (u32*)(wt + byo);
    dst[0] = pk2(w4.x, w4.y);
    dst[1] = pk2(w4.z, w4.w);
  } else {
    int tid = (bid - 2048) * 256 + threadIdx.x;   // 16384 threads
    int e  = tid & 127;
    int bc = tid >> 7;
    int b  = bc >> 5;
    int ch = bc & 31;
    int t0 = ch * 64;
    const float* xb = x + (long)b * 2048 * 128 + e;
    float* sb = st + (long)e * 8192 + b * 2048;
    const float inv = 1.0f / 1.2f;
    float c = 0.f;
    if (ch > 0) {
      const float* xp = xb + (long)(t0 - 64) * 128;
      #pragma unroll
      for (int t = 0; t < 64; ++t) c = (c + xp[t * 128]) * inv;
    }
    const float* xq = xb + (long)t0 * 128;
    float* sq = sb + t0;
    #pragma unroll
    for (int t = 0; t < 64; ++t) { sq[t] = c; c = (c + xq[t * 128]) * inv; }
  }
}

// ---- final reduce: out = sum over 4 K-split partials ----------------------
__global__ void k_red(const float4* __restrict__ part, float4* __restrict__ out) {
  int i = blockIdx.x * 256 + threadIdx.x;          // 262144 float4
  float4 a = part[i];
  float4 b = part[i + 262144];
  float4 c = part[i + 524288];
  float4 d = part[i + 786432];
  out[i] = make_float4(a.x + b.x + c.x + d.x, a.y + b.y + c.y + d.y,
                       a.z + b.z + c.z + d.z, a.w + b.w + c.w + d.w);
}

// ======================= ABLATION PROBES (diagnostic) =======================
// R7 skeleton x REP repeats so every variant exceeds k_main's 51us and shows
// in the top-5 table. Occupancy-pinned to production (same LDS, same bounds).
// MODE 0: full. 1: no-B. 2: no-A. 3: MFMA-only. Laundered consts (rule 17).
template <int MODE, int NT, int REP>
__global__ __launch_bounds__(512, 2) void k_probe(
    const float* __restrict__ x, const float* __restrict__ st,
    const char* __restrict__ wt, float* __restrict__ scratch) {
  __shared__ u32 x_lds[128 * 36];      // 18.4KB (same as production)
  __shared__ float red[128 * 129];     // 66KB occupancy ballast (used at end)

  const int tid  = threadIdx.x;
  const int bid  = blockIdx.x;
  const int kq   = bid & 3;
  const int tt   = bid >> 2;
  const int wv   = tid >> 6;
  const int lane = tid & 63;
  const int ng   = wv & 1;
  const int ep   = wv >> 1;
  const int r    = lane & 15;
  const int kg   = lane >> 4;
  const int tokenBase = tt * 128;

  if constexpr (MODE <= 1) {
    int row = tid >> 2, c0 = (tid & 3) * 8;
    const float* src = x + (long)(tokenBase + row) * 128 + kq * 32 + c0;
    float4 v0 = *(const float4*)src;
    float4 v1 = *(const float4*)(src + 4);
    u32* dst = &x_lds[row * 36 + c0];
    dst[0] = pk2(v0.x, v0.x); dst[1] = pk2(v0.y, v0.y);
    dst[2] = pk2(v0.z, v0.z); dst[3] = pk2(v0.w, v0.w);
    dst[4] = pk2(v1.x, v1.x); dst[5] = pk2(v1.y, v1.y);
    dst[6] = pk2(v1.z, v1.z); dst[7] = pk2(v1.w, v1.w);
  }
  u32 sreg[8][4];
  if constexpr (MODE <= 1) {
    const float* stb = st + tokenBase + (long)(ep * 32 + kg * 8) * 8192;
    #pragma unroll
    for (int mr = 0; mr < 8; ++mr)
      #pragma unroll
      for (int jj = 0; jj < 4; ++jj) {
        const float* qp = stb + (long)(2 * jj) * 8192 + mr * 16 + r;
        sreg[mr][jj] = pk2(qp[0], qp[8192]);
      }
  }
  __syncthreads();

  u32 lz = 0x34003400u;
  __asm__ volatile("" : "+v"(lz));      // opaque: no fold/DCE
  f16x8 bconst, aconst;
  {
    union { u32 u[4]; f16x8 v; } t;
    t.u[0] = lz; t.u[1] = lz; t.u[2] = lz; t.u[3] = lz;
    bconst = t.v; aconst = t.v;
  }

  f32x4 acc[8][4];
  #pragma unroll
  for (int mr = 0; mr < 8; ++mr)
    #pragma unroll
    for (int n = 0; n < 4; ++n) acc[mr][n] = (f32x4){0.f, 0.f, 0.f, 0.f};

  const char* wtq = wt + (long)(kq * 32) * 32768 + ep * 8192 + ng * 4096;
  const int loff = r * 64 + kg * 16;

#define PSTEP(BUF, XB, J)                                                    \
  {                                                                          \
    _Pragma("unroll")                                                        \
    for (int mr = 0; mr < 8; ++mr) {                                         \
      union { u32 u[4]; f16x8 v; } au;                                       \
      if constexpr (MODE <= 1) {                                             \
        f16x2 xv2;                                                           \
        *(u32*)&xv2 = XB[mr][J];                                             \
        _Pragma("unroll")                                                    \
        for (int jj = 0; jj < 4; ++jj) {                                     \
          f16x2 s2;                                                          \
          *(u32*)&s2 = sreg[mr][jj];                                         \
          f16x2 p = xv2 * s2;                                                \
          au.u[jj] = *(u32*)&p;                                              \
        }                                                                    \
      } else {                                                               \
        au.v = aconst;                                                       \
      }                                                                      \
      _Pragma("unroll")                                                      \
      for (int n = 0; n < 4; ++n)                                            \
        acc[mr][n] = __builtin_amdgcn_mfma_f32_16x16x32_f16(                 \
            au.v, (MODE == 0 || MODE == 2) ? BUF[n] : bconst,                \
            acc[mr][n], 0, 0, 0);                                            \
    }                                                                        \
  }
#define PBLOAD(BUF, IT)                                                      \
  if constexpr (MODE == 0 || MODE == 2) {                                    \
    int itc = (IT) > 31 ? 31 : (IT);                                         \
    const char* wn = wtq + (long)itc * 32768;                                \
    _Pragma("unroll")                                                        \
    for (int n = 0; n < 4; ++n)                                              \
      BUF[n] = *(const f16x8*)(wn + n * 1024 + loff);                        \
  }

  f16x8 ba[4], bb[4];
  PBLOAD(ba, 0);

  #pragma unroll 1
  for (int rp = 0; rp < REP; ++rp) {
    #pragma unroll 1
    for (int it4 = 0; it4 < NT; ++it4) {
      u32x4 xb[8];
      if constexpr (MODE <= 1) {
        #pragma unroll
        for (int mr = 0; mr < 8; ++mr)
          xb[mr] = *(const u32x4*)&x_lds[(mr * 16 + r) * 36 + it4 * 4];
      }
      int it = it4 * 4;
      PBLOAD(bb, it + 1); PSTEP(ba, xb, 0);
      PBLOAD(ba, it + 2); PSTEP(bb, xb, 1);
      PBLOAD(bb, it + 3); PSTEP(ba, xb, 2);
      PBLOAD(ba, it + 4); PSTEP(bb, xb, 3);
    }
  }
#undef PSTEP
#undef PBLOAD

  float ssum = 0.f;
  #pragma unroll
  for (int mr = 0; mr < 8; ++mr)
    #pragma unroll
    for (int n = 0; n < 4; ++n)
      #pragma unroll
      for (int q2 = 0; q2 < 4; ++q2) ssum += acc[mr][n][q2];
  red[tid] = ssum;                     // keep ballast LDS live
  __syncthreads();
  scratch[(long)bid * 512 + tid] = red[tid];
}

// ================= production main (R7 structure, fastest so far) ==========
__global__ __launch_bounds__(512, 2) void k_main(
    const float* __restrict__ x, const float* __restrict__ st,
    const char* __restrict__ wt, float* __restrict__ part) {
  __shared__ u32 x_lds[128 * 36];
  __shared__ float red[128 * 129];

  const int tid  = threadIdx.x;
  const int bid  = blockIdx.x;
  const int kq   = bid & 3;
  const int tt   = bid >> 2;
  const int wv   = tid >> 6;
  const int lane = tid & 63;
  const int ng   = wv & 1;
  const int ep   = wv >> 1;
  const int r    = lane & 15;
  const int kg   = lane >> 4;
  const int tokenBase = tt * 128;

  {
    int row = tid >> 2, c0 = (tid & 3) * 8;
    const float* src = x + (long)(tokenBase + row) * 128 + kq * 32 + c0;
    float4 v0 = *(const float4*)src;
    float4 v1 = *(const float4*)(src + 4);
    u32* dst = &x_lds[row * 36 + c0];
    dst[0] = pk2(v0.x, v0.x); dst[1] = pk2(v0.y, v0.y);
    dst[2] = pk2(v0.z, v0.z); dst[3] = pk2(v0.w, v0.w);
    dst[4] = pk2(v1.x, v1.x); dst[5] = pk2(v1.y, v1.y);
    dst[6] = pk2(v1.z, v1.z); dst[7] = pk2(v1.w, v1.w);
  }
  u32 sreg[8][4];
  {
    const float* stb = st + tokenBase + (long)(ep * 32 + kg * 8) * 8192;
    #pragma unroll
    for (int mr = 0; mr < 8; ++mr)
      #pragma unroll
      for (int jj = 0; jj < 4; ++jj) {
        const float* qp = stb + (long)(2 * jj) * 8192 + mr * 16 + r;
        sreg[mr][jj] = pk2(qp[0], qp[8192]);
      }
  }
  __syncthreads();

  f32x4 acc[8][4];
  #pragma unroll
  for (int mr = 0; mr < 8; ++mr)
    #pragma unroll
    for (int n = 0; n < 4; ++n) acc[mr][n] = (f32x4){0.f, 0.f, 0.f, 0.f};

  const char* wtq = wt + (long)(kq * 32) * 32768 + ep * 8192 + ng * 4096;
  const int loff = r * 64 + kg * 16;

#define STEP(BUF, XB, J)                                                     \
  {                                                                          \
    _Pragma("unroll")                                                        \
    for (int mr = 0; mr < 8; ++mr) {                                         \
      f16x2 xv2;                                                             \
      *(u32*)&xv2 = XB[mr][J];                                               \
      union { u32 u[4]; f16x8 v; } au;                                       \
      _Pragma("unroll")                                                      \
      for (int jj = 0; jj < 4; ++jj) {                                       \
        f16x2 s2;                                                            \
        *(u32*)&s2 = sreg[mr][jj];                                           \
        f16x2 p = xv2 * s2;                                                  \
        au.u[jj] = *(u32*)&p;                                                \
      }                                                                      \
      _Pragma("unroll")                                                      \
      for (int n = 0; n < 4; ++n)                                            \
        acc[mr][n] = __builtin_amdgcn_mfma_f32_16x16x32_f16(                 \
            au.v, BUF[n], acc[mr][n], 0, 0, 0);                              \
    }                                                                        \
  }
#define BLOAD(BUF, IT)                                                       \
  {                                                                          \
    int itc = (IT) > 31 ? 31 : (IT);                                         \
    const char* wn = wtq + (long)itc * 32768;                                \
    _Pragma("unroll")                                                        \
    for (int n = 0; n < 4; ++n)                                              \
      BUF[n] = *(const f16x8*)(wn + n * 1024 + loff);                        \
  }

  f16x8 ba[4], bb[4];
  BLOAD(ba, 0);

  #pragma unroll 1
  for (int it4 = 0; it4 < 8; ++it4) {
    u32x4 xb[8];
    #pragma unroll
    for (int mr = 0; mr < 8; ++mr)
      xb[mr] = *(const u32x4*)&x_lds[(mr * 16 + r) * 36 + it4 * 4];
    int it = it4 * 4;
    BLOAD(bb, it + 1); STEP(ba, xb, 0);
    BLOAD(ba, it + 2); STEP(bb, xb, 1);
    BLOAD(bb, it + 3); STEP(ba, xb, 2);
    BLOAD(ba, it + 4); STEP(bb, xb, 3);
  }
#undef STEP
#undef BLOAD

  __syncthreads();
  #pragma unroll
  for (int round = 0; round < 4; ++round) {
    if (ep == round) {
      #pragma unroll
      for (int mr = 0; mr < 8; ++mr)
        #pragma unroll
        for (int n = 0; n < 4; ++n)
          #pragma unroll
          for (int q2 = 0; q2 < 4; ++q2) {
            int idx = (mr * 16 + kg * 4 + q2) * 129 + ng * 64 + n * 16 + r;
            if (round == 0) red[idx] = acc[mr][n][q2];
            else            red[idx] += acc[mr][n][q2];
          }
    }
    __syncthreads();
  }
  float* outp = part + (long)kq * 1048576 + (long)tokenBase * 128;
  #pragma unroll
  for (int j = 0; j < 32; ++j) {
    int row = (tid >> 7) + j * 4;
    int col = tid & 127;
    outp[row * 128 + col] = red[row * 129 + col];
  }
}

extern "C" void kernel_launch(void* const* d_in, const int* in_sizes, int n_in,
                              void* d_out, int out_size, void* d_ws, size_t ws_size,
                              hipStream_t stream) {
  const float* x = (const float*)d_in[0];        // [4,2048,128] f32
  const float* W = (const float*)d_in[1];        // [128,128,128] f32
  float* out  = (float*)d_out;                   // [4,2048,128] f32
  float* st   = (float*)d_ws;                    // 4 MB: s transposed [e][token]
  char*  wt   = (char*)d_ws + (4 << 20);         // 4 MB: W fp16 retiled
  float* part = (float*)((char*)d_ws + (8 << 20)); // 16 MB: partials (probes
                                                   // scribble; k_main overwrites)

  k_pre <<<dim3(2112), dim3(256), 0, stream>>>(W, wt, x, st);
  // diagnostic probes, REP=4 so each exceeds k_main and shows in top-5:
  k_probe<0, 8, 4><<<dim3(256), dim3(512), 0, stream>>>(x, st, wt, part); // full
  k_probe<1, 8, 4><<<dim3(256), dim3(512), 0, stream>>>(x, st, wt, part); // no-B
  k_probe<2, 8, 4><<<dim3(256), dim3(512), 0, stream>>>(x, st, wt, part); // no-A
  k_probe<3, 8, 4><<<dim3(256), dim3(512), 0, stream>>>(x, st, wt, part); // MFMA-only
  // production
  k_main<<<dim3(256), dim3(512), 0, stream>>>(x, st, wt, part);
  k_red <<<dim3(1024), dim3(256), 0, stream>>>((const float4*)part, (float4*)out);
}

// Round 12
// 57.288 us; speedup vs baseline: 6.0099x; 6.0099x over previous
//
#include <hip/hip_runtime.h>

typedef _Float16 f16;
typedef _Float16 f16x2 __attribute__((ext_vector_type(2)));
typedef _Float16 f16x8 __attribute__((ext_vector_type(8)));
typedef float f32x16 __attribute__((ext_vector_type(16)));
typedef unsigned int u32;
typedef unsigned int u32x4 __attribute__((ext_vector_type(4)));

static __device__ __forceinline__ u32 pk2(float lo, float hi) {
  union { f16 h[2]; u32 u; } v;
  v.h[0] = (f16)lo; v.h[1] = (f16)hi;
  return v.u;
}

// ---- fused prep: blocks 0..2047: W[f,d,e]->fp16 retile;
//      blocks 2048..2111: decayed prefix scan of x -> st (transposed).
// W layout: byte = d*32768 + (e>>5)*8192 + f*64 + ((e>>3)&3)*16 + (e&7)*2
__global__ void k_pre(const float* __restrict__ W, char* __restrict__ wt,
                      const float* __restrict__ x, float* __restrict__ st) {
  int bid = blockIdx.x;
  if (bid < 2048) {
    int t = bid * 256 + threadIdx.x;
    long i = (long)t * 4;                      // 2M W elements, 4/thread
    int f = (int)(i >> 14);
    int k = (int)(i & 16383);
    float4 w4 = *(const float4*)(W + i);
    int d = k >> 7, e = k & 127;
    long byo = (long)d * 32768 + (e >> 5) * 8192 + f * 64 + ((e >> 3) & 3) * 16 + (e & 7) * 2;
    u32* dst = (u32*)(wt + byo);
    dst[0] = pk2(w4.x, w4.y);
    dst[1] = pk2(w4.z, w4.w);
  } else {
    int tid = (bid - 2048) * 256 + threadIdx.x;   // 16384 threads
    int e  = tid & 127;
    int bc = tid >> 7;
    int b  = bc >> 5;
    int ch = bc & 31;
    int t0 = ch * 64;
    const float* xb = x + (long)b * 2048 * 128 + e;
    float* sb = st + (long)e * 8192 + b * 2048;
    const float inv = 1.0f / 1.2f;
    float c = 0.f;
    if (ch > 0) {
      const float* xp = xb + (long)(t0 - 64) * 128;
      #pragma unroll
      for (int t = 0; t < 64; ++t) c = (c + xp[t * 128]) * inv;
    }
    const float* xq = xb + (long)t0 * 128;
    float* sq = sb + t0;
    #pragma unroll
    for (int t = 0; t < 64; ++t) { sq[t] = c; c = (c + xq[t * 128]) * inv; }
  }
}

// ---- final reduce: out = sum over 4 K-split partials ----------------------
__global__ void k_red(const float4* __restrict__ part, float4* __restrict__ out) {
  int i = blockIdx.x * 256 + threadIdx.x;          // 262144 float4
  float4 a = part[i];
  float4 b = part[i + 262144];
  float4 c = part[i + 524288];
  float4 d = part[i + 786432];
  out[i] = make_float4(a.x + b.x + c.x + d.x, a.y + b.y + c.y + d.y,
                       a.z + b.z + c.z + d.z, a.w + b.w + c.w + d.w);
}

// ---------------- main: part[kq][token,f] = sum_{d in kq} (x*s) W ----------
// grid 256 = 64 token-tiles (BM=128) x K-split 4 -> 1 block/CU. 8 waves =
// f-half(ng) x e-quadrant(ep): disjoint W slices, 256MB L2 traffic.
// MFMA shape: 32x32x16 f16 (R11 ablation: clean 16x16 loop capped at 58%;
// 32x32 occupies the matrix pipe 33.8cyc/inst -> saturates at low TLP;
// ubench 95-99.8% of peak vs 83% for 16x16). Wave tile 128tok x 64f x 32e:
// acc = 4m x 2n x f32x16 = 128 regs. A: row=lane&31, k=(lane>>5)*8+j;
// B: col=lane&31, same k; C/D: col=lane&31, row=(reg&3)+8*(reg>>2)+4*hi.
__global__ __launch_bounds__(512, 2) void k_main(
    const float* __restrict__ x, const float* __restrict__ st,
    const char* __restrict__ wt, float* __restrict__ part) {
  __shared__ u32 x_lds[128 * 36];        // 18KB half2(x,x) [128 tok][pad36]
  __shared__ float red[128 * 129];       // 66KB padded epilogue reduction

  const int tid  = threadIdx.x;
  const int bid  = blockIdx.x;
  const int kq   = bid & 3;          // K-quarter: d in [kq*32, kq*32+32)
  const int tt   = bid >> 2;         // token tile (0..63)
  const int wv   = tid >> 6;         // 0..7
  const int lane = tid & 63;
  const int ng   = wv & 1;           // f half
  const int ep   = wv >> 1;          // e quadrant
  const int l31  = lane & 31;
  const int hi   = lane >> 5;
  const int tokenBase = tt * 128;

  // stage x tile as duplicated half2 (xv,xv): [128 tok][32 d], d = kq*32+it
  {
    int row = tid >> 2, c0 = (tid & 3) * 8;
    const float* src = x + (long)(tokenBase + row) * 128 + kq * 32 + c0;
    float4 v0 = *(const float4*)src;
    float4 v1 = *(const float4*)(src + 4);
    u32* dst = &x_lds[row * 36 + c0];
    dst[0] = pk2(v0.x, v0.x); dst[1] = pk2(v0.y, v0.y);
    dst[2] = pk2(v0.z, v0.z); dst[3] = pk2(v0.w, v0.w);
    dst[4] = pk2(v1.x, v1.x); dst[5] = pk2(v1.y, v1.y);
    dst[6] = pk2(v1.z, v1.z); dst[7] = pk2(v1.w, v1.w);
  }

  // s: lane needs s[token = m*32+l31][e = ep*32 + kk*16 + hi*8 + j] packed
  // as half2 pairs -> sreg[m][kk][jj], 32 VGPRs.
  u32 sreg[4][2][4];
  {
    #pragma unroll
    for (int m = 0; m < 4; ++m)
      #pragma unroll
      for (int kk = 0; kk < 2; ++kk)
        #pragma unroll
        for (int jj = 0; jj < 4; ++jj) {
          const float* qp = st + (long)(ep * 32 + kk * 16 + hi * 8 + 2 * jj) * 8192
                              + tokenBase + m * 32 + l31;
          sreg[m][kk][jj] = pk2(qp[0], qp[8192]);
        }
  }
  __syncthreads();   // x_lds ready; only barrier before epilogue

  f32x16 acc[4][2];
  #pragma unroll
  for (int m = 0; m < 4; ++m)
    #pragma unroll
    for (int n = 0; n < 2; ++n)
      #pragma unroll
      for (int q = 0; q < 16; ++q) acc[m][n][q] = 0.f;

  // wtq includes ng: f = ng*64 + n*32 + l31 -> (n*32+l31)*64 within chunk
  const char* wtq = wt + (long)(kq * 32) * 32768 + ep * 8192 + ng * 4096;
  const int lboff = l31 * 64 + hi * 16;

  // B frags for one d-step: [kk][n] at wn + n*2048 + kk*32 + lboff
#define BLOAD(BUF, IT)                                                       \
  {                                                                          \
    int itc = (IT) > 31 ? 31 : (IT);                                         \
    const char* wn = wtq + (long)itc * 32768;                                \
    BUF[0][0] = *(const f16x8*)(wn + lboff);                                 \
    BUF[0][1] = *(const f16x8*)(wn + 2048 + lboff);                          \
    BUF[1][0] = *(const f16x8*)(wn + 32 + lboff);                            \
    BUF[1][1] = *(const f16x8*)(wn + 2048 + 32 + lboff);                     \
  }
  // one d-step: per (kk,m) gen A-frag (4 pk_mul) then 2 MFMAs
#define STEP(BUF, XB, J)                                                     \
  {                                                                          \
    _Pragma("unroll")                                                        \
    for (int kk = 0; kk < 2; ++kk) {                                         \
      _Pragma("unroll")                                                      \
      for (int m = 0; m < 4; ++m) {                                          \
        f16x2 xv2;                                                           \
        *(u32*)&xv2 = XB[m][J];                                              \
        union { u32 u[4]; f16x8 v; } au;                                     \
        _Pragma("unroll")                                                    \
        for (int jj = 0; jj < 4; ++jj) {                                     \
          f16x2 s2;                                                          \
          *(u32*)&s2 = sreg[m][kk][jj];                                      \
          f16x2 p = xv2 * s2;                                                \
          au.u[jj] = *(u32*)&p;                                              \
        }                                                                    \
        acc[m][0] = __builtin_amdgcn_mfma_f32_32x32x16_f16(                  \
            au.v, BUF[kk][0], acc[m][0], 0, 0, 0);                           \
        acc[m][1] = __builtin_amdgcn_mfma_f32_32x32x16_f16(                  \
            au.v, BUF[kk][1], acc[m][1], 0, 0, 0);                           \
      }                                                                      \
    }                                                                        \
  }

  f16x8 ba[2][2], bb[2][2];
  BLOAD(ba, 0);

  #pragma unroll 1
  for (int it4 = 0; it4 < 8; ++it4) {
    // batched x: one ds_read_b128 per m covers 4 d-steps
    u32x4 xb[4];
    #pragma unroll
    for (int m = 0; m < 4; ++m)
      xb[m] = *(const u32x4*)&x_lds[(m * 32 + l31) * 36 + it4 * 4];
    int it = it4 * 4;
    BLOAD(bb, it + 1); STEP(ba, xb, 0);
    BLOAD(ba, it + 2); STEP(bb, xb, 1);
    BLOAD(bb, it + 3); STEP(ba, xb, 2);
    BLOAD(ba, it + 4); STEP(bb, xb, 3);
  }
#undef STEP
#undef BLOAD

  // epilogue: reduce the 4 e-quadrant waves (per f-half) in LDS, then store
  __syncthreads();
  #pragma unroll
  for (int round = 0; round < 4; ++round) {
    if (ep == round) {
      #pragma unroll
      for (int m = 0; m < 4; ++m)
        #pragma unroll
        for (int n = 0; n < 2; ++n)
          #pragma unroll
          for (int reg = 0; reg < 16; ++reg) {
            // C/D: col=l31 (f), row=(reg&3)+8*(reg>>2)+4*hi (token)
            int token = m * 32 + (reg & 3) + 8 * (reg >> 2) + 4 * hi;
            int idx = token * 129 + ng * 64 + n * 32 + l31;
            if (round == 0) red[idx] = acc[m][n][reg];
            else            red[idx] += acc[m][n][reg];
          }
    }
    __syncthreads();
  }
  // plain coalesced stores to this kq's private partial slice
  float* outp = part + (long)kq * 1048576 + (long)tokenBase * 128;
  #pragma unroll
  for (int j = 0; j < 32; ++j) {
    int row = (tid >> 7) + j * 4;
    int col = tid & 127;
    outp[row * 128 + col] = red[row * 129 + col];
  }
}

extern "C" void kernel_launch(void* const* d_in, const int* in_sizes, int n_in,
                              void* d_out, int out_size, void* d_ws, size_t ws_size,
                              hipStream_t stream) {
  const float* x = (const float*)d_in[0];        // [4,2048,128] f32
  const float* W = (const float*)d_in[1];        // [128,128,128] f32
  float* out  = (float*)d_out;                   // [4,2048,128] f32
  float* st   = (float*)d_ws;                    // 4 MB: s transposed [e][token]
  char*  wt   = (char*)d_ws + (4 << 20);         // 4 MB: W fp16 retiled
  float* part = (float*)((char*)d_ws + (8 << 20)); // 16 MB: K-split partials

  k_pre <<<dim3(2112), dim3(256), 0, stream>>>(W, wt, x, st);
  k_main<<<dim3(256),  dim3(512), 0, stream>>>(x, st, wt, part);
  k_red <<<dim3(1024), dim3(256), 0, stream>>>((const float4*)part, (float4*)out);
}